// Round 13
// baseline (387.435 us; speedup 1.0000x reference)
//
#include <hip/hip_runtime.h>
#include <hip/hip_cooperative_groups.h>
#include <math.h>

namespace cg = cooperative_groups;

#define F 128
#define OUT 128
#define PST 136
#define GOST 264
#define FOST 280

typedef unsigned short ushort_t;
typedef __attribute__((ext_vector_type(8))) short bfrag;   // 8 bf16
typedef __attribute__((ext_vector_type(4))) float ffrag;   // 4 fp32 acc

__device__ __forceinline__ float bf_lo(unsigned int u) {
    return __uint_as_float(u << 16);
}
__device__ __forceinline__ float bf_hi(unsigned int u) {
    return __uint_as_float(u & 0xffff0000u);
}
__device__ __forceinline__ ushort_t f2bf(float f) {
    unsigned int x = __float_as_uint(f);
    unsigned int r = x + 0x7fffu + ((x >> 16) & 1u);
    return (ushort_t)(r >> 16);
}
__device__ __forceinline__ unsigned pk2(float lo, float hi) {
    return (unsigned)f2bf(lo) | ((unsigned)f2bf(hi) << 16);
}

// ===========================================================================
// Cooperative giga kernel: 4 phases with grid.sync().
// ===========================================================================
__global__ __launch_bounds__(256, 4) void giga_kernel(
    const float* __restrict__ feat, const float* __restrict__ w1,
    const float* __restrict__ b1, const float* __restrict__ w2,
    const float* __restrict__ wf, const float* __restrict__ bfv,
    const int* __restrict__ src, const int* __restrict__ dst,
    float* __restrict__ out,
    ushort_t* __restrict__ abig, ushort_t* __restrict__ e_dst,
    ushort_t* __restrict__ srcpack, ushort_t* __restrict__ btp,
    ushort_t* __restrict__ btf, int* __restrict__ row_ptr,
    int n, int e)
{
    cg::grid_group grid = cg::this_grid();
    const int nb = gridDim.x;
    const int b = blockIdx.x, t = threadIdx.x;
    const int wv = t >> 6, lane = t & 63;
    const int lm = lane & 15, quad = lane >> 4;

    __shared__ __align__(16) unsigned char smem[16384];
    ushort_t* As = (ushort_t*)smem;                    // P1: 4352B; P3: 8448B
    ushort_t* Ep = (ushort_t*)(smem + 4352);           // P1: 4 x 2560B

    // ================= Phase 0: prep =================
    for (int i = b * 256 + t; i < n * 16; i += nb * 256) {
        int row = i >> 4, c = (i & 15) * 8;
        float4 a = *(const float4*)(feat + (size_t)row * F + c);
        float4 bb = *(const float4*)(feat + (size_t)row * F + c + 4);
        *(uint4*)(abig + (size_t)row * 256 + c) =
            make_uint4(pk2(a.x, a.y), pk2(a.z, a.w), pk2(bb.x, bb.y), pk2(bb.z, bb.w));
    }
    for (int idx = b * 256 + t; idx < 32768; idx += nb * 256) {
        int j = idx >> 7, k = idx & 127;
        float v = (j < F) ? w1[(size_t)k * F + j]
                          : w1[(size_t)(F + k) * F + (j - F)];
        btp[idx] = f2bf(v);
    }
    for (int idx = b * 256 + t; idx < 32768; idx += nb * 256) {
        int j = idx >> 8, k = idx & 255;
        btf[idx] = f2bf(wf[(size_t)k * F + j]);
    }
    for (int i = b * 256 + t; i < e; i += nb * 256) {
        int d = dst[i];
        int prev = (i == 0) ? -1 : dst[i - 1];
        for (int v = prev + 1; v <= d; ++v) row_ptr[v] = i;
        if (i == e - 1) {
            for (int v = d + 1; v <= n; ++v) row_ptr[v] = e;
        }
    }
    grid.sync();

    // ================= Phase 1: proj GEMM (16-row tiles) =================
    const int ntile = (n + 15) / 16;     // n % 16 == 0
    const int col0 = wv * 64;
    for (int tile = b; tile < ntile; tile += nb) {
        const int row0 = tile * 16;
        {   // stage 16 rows x 16 uint4, coalesced
            int r = t >> 4, ch = t & 15;
            uint4 d = *(const uint4*)(abig + (size_t)(row0 + r) * 256 + ch * 8);
            *(uint4*)(As + r * PST + ch * 8) = d;
        }
        __syncthreads();

        ffrag acc[4];
#pragma unroll
        for (int ni = 0; ni < 4; ++ni) acc[ni] = (ffrag){0.f, 0.f, 0.f, 0.f};
#pragma unroll
        for (int ks = 0; ks < 4; ++ks) {
            bfrag af = *(const bfrag*)(As + lm * PST + ks * 32 + quad * 8);
#pragma unroll
            for (int ni = 0; ni < 4; ++ni) {
                bfrag bv = *(const bfrag*)(btp + (size_t)(col0 + ni * 16 + lm) * 128
                                           + ks * 32 + quad * 8);
                acc[ni] = __builtin_amdgcn_mfma_f32_16x16x32_bf16(af, bv, acc[ni], 0, 0, 0);
            }
        }

#pragma unroll
        for (int ni = 0; ni < 4; ++ni) {
            const float bias = (col0 < F) ? b1[col0 + ni * 16 + lm] : 0.f;
#pragma unroll
            for (int r = 0; r < 4; ++r)
                Ep[wv * 1280 + (quad * 4 + r) * 80 + ni * 16 + lm] =
                    f2bf(__expf(2.f * (acc[ni][r] + bias)));
        }

        if (col0 < F) {
#pragma unroll
            for (int ps = 0; ps < 2; ++ps) {
                int rl = ps * 8 + (lane >> 3), co = (lane & 7) * 8;
                uint4 vv = *(const uint4*)(&Ep[wv * 1280 + rl * 80 + co]);
                *(uint4*)(e_dst + (size_t)(row0 + rl) * F + col0 + co) = vv;
            }
        } else {
            const int cbase = (col0 - F) >> 2;
#pragma unroll
            for (int ps = 0; ps < 4; ++ps) {
                int rl = ps * 4 + (lane >> 4);
                int c  = lane & 15;
                int cg2 = cbase + c;
                uint2 es = *(const uint2*)(&Ep[wv * 1280 + rl * 80 + c * 4]);
                uint2 ft = *(const uint2*)(As + rl * PST + cg2 * 4);
                *(uint4*)(srcpack + (size_t)(row0 + rl) * 256 + cg2 * 8) =
                    make_uint4(es.x, es.y, ft.x, ft.y);
            }
        }
        __syncthreads();
    }
    grid.sync();

    // ================= Phase 2: fused score+softmax+agg =================
    {
        const int fl = t & 31;
        const int sbase = t & 32;
        const float4 wv4 = ((const float4*)w2)[fl];
        const float w0 = wv4.x, w1_ = wv4.y, w2_ = wv4.z, w3_ = wv4.w;
        float sw = w0 + w1_ + w2_ + w3_;
        float aw = fabsf(w0) + fabsf(w1_) + fabsf(w2_) + fabsf(w3_);
#pragma unroll
        for (int off = 16; off; off >>= 1) {
            sw += __shfl_xor(sw, off, 64);
            aw += __shfl_xor(aw, off, 64);
        }
        const float K = sw - aw;

        const int ngrp = (n + 7) / 8;
        for (int g = b; g < ngrp; g += nb) {
            const int v = g * 8 + (t >> 5);
            const int begin = row_ptr[v], end = row_ptr[v + 1];

            const uint2 ud = *(const uint2*)(e_dst + (size_t)v * F + fl * 4);
            const float ea0 = bf_lo(ud.x), ea1 = bf_hi(ud.x);
            const float ea2 = bf_lo(ud.y), ea3 = bf_hi(ud.y);

            float s = 0.f, a0 = 0.f, a1 = 0.f, a2 = 0.f, a3 = 0.f;

            for (int cb = begin; cb < end; cb += 32) {
                const int clen = min(32, end - cb);
                const int sv = (fl < clen) ? src[cb + fl] : 0;
                int jj = 0;
                for (; jj + 4 <= clen; jj += 4) {
                    uint4 u[4];
#pragma unroll
                    for (int q = 0; q < 4; ++q) {
                        const int sq = __shfl(sv, sbase + jj + q, 64);
                        u[q] = ((const uint4*)(srcpack + (size_t)sq * 256))[fl];
                    }
                    float p[4];
#pragma unroll
                    for (int q = 0; q < 4; ++q) {
                        float r;
                        r = __builtin_amdgcn_rcpf(fmaf(ea0, bf_lo(u[q].x), 1.f)); p[q] = w0 * r;
                        r = __builtin_amdgcn_rcpf(fmaf(ea1, bf_hi(u[q].x), 1.f)); p[q] = fmaf(w1_, r, p[q]);
                        r = __builtin_amdgcn_rcpf(fmaf(ea2, bf_lo(u[q].y), 1.f)); p[q] = fmaf(w2_, r, p[q]);
                        r = __builtin_amdgcn_rcpf(fmaf(ea3, bf_hi(u[q].y), 1.f)); p[q] = fmaf(w3_, r, p[q]);
                    }
#pragma unroll
                    for (int off = 16; off; off >>= 1) {
#pragma unroll
                        for (int q = 0; q < 4; ++q) p[q] += __shfl_xor(p[q], off, 64);
                    }
                    float gq[4];
#pragma unroll
                    for (int q = 0; q < 4; ++q) gq[q] = __expf(fmaf(-2.f, p[q], K));
                    s += (gq[0] + gq[1]) + (gq[2] + gq[3]);
#pragma unroll
                    for (int q = 0; q < 4; ++q) {
                        a0 = fmaf(gq[q], bf_lo(u[q].z), a0);
                        a1 = fmaf(gq[q], bf_hi(u[q].z), a1);
                        a2 = fmaf(gq[q], bf_lo(u[q].w), a2);
                        a3 = fmaf(gq[q], bf_hi(u[q].w), a3);
                    }
                }
                for (; jj < clen; ++jj) {
                    const int s0 = __shfl(sv, sbase + jj, 64);
                    const uint4 u0 = ((const uint4*)(srcpack + (size_t)s0 * 256))[fl];
                    float r, p0;
                    r = __builtin_amdgcn_rcpf(fmaf(ea0, bf_lo(u0.x), 1.f)); p0 = w0 * r;
                    r = __builtin_amdgcn_rcpf(fmaf(ea1, bf_hi(u0.x), 1.f)); p0 = fmaf(w1_, r, p0);
                    r = __builtin_amdgcn_rcpf(fmaf(ea2, bf_lo(u0.y), 1.f)); p0 = fmaf(w2_, r, p0);
                    r = __builtin_amdgcn_rcpf(fmaf(ea3, bf_hi(u0.y), 1.f)); p0 = fmaf(w3_, r, p0);
#pragma unroll
                    for (int off = 16; off; off >>= 1) p0 += __shfl_xor(p0, off, 64);
                    const float g0 = __expf(fmaf(-2.f, p0, K));
                    s += g0;
                    a0 = fmaf(g0, bf_lo(u0.z), a0);
                    a1 = fmaf(g0, bf_hi(u0.z), a1);
                    a2 = fmaf(g0, bf_lo(u0.w), a2);
                    a3 = fmaf(g0, bf_hi(u0.w), a3);
                }
            }

            const float inv = (end > begin) ? 1.f / s : 0.f;
            *(ushort4*)(abig + (size_t)v * 256 + 128 + fl * 4) =
                make_ushort4(f2bf(a0 * inv), f2bf(a1 * inv),
                             f2bf(a2 * inv), f2bf(a3 * inv));
        }
    }
    grid.sync();

    // ================= Phase 3: out GEMM (16-row tiles) =================
    const int col0g = wv * 32;
    for (int tile = b; tile < ntile; tile += nb) {
        const int row0 = tile * 16;
#pragma unroll
        for (int k = 0; k < 2; ++k) {
            int l = k * 256 + t;
            int r = l >> 5, ch = l & 31;
            uint4 d = *(const uint4*)(abig + (size_t)(row0 + r) * 256 + ch * 8);
            *(uint4*)(As + r * GOST + ch * 8) = d;
        }
        __syncthreads();

        ffrag acc[2];
#pragma unroll
        for (int ni = 0; ni < 2; ++ni) acc[ni] = (ffrag){0.f, 0.f, 0.f, 0.f};
#pragma unroll
        for (int ks = 0; ks < 8; ++ks) {
            bfrag af = *(const bfrag*)(As + lm * GOST + ks * 32 + quad * 8);
#pragma unroll
            for (int ni = 0; ni < 2; ++ni) {
                bfrag bv = *(const bfrag*)(btf + (size_t)(col0g + ni * 16 + lm) * 256
                                           + ks * 32 + quad * 8);
                acc[ni] = __builtin_amdgcn_mfma_f32_16x16x32_bf16(af, bv, acc[ni], 0, 0, 0);
            }
        }

#pragma unroll
        for (int ni = 0; ni < 2; ++ni) {
            const int j = col0g + ni * 16 + lm;
            const float bb = bfv[j];
#pragma unroll
            for (int r = 0; r < 4; ++r)
                out[(size_t)(row0 + quad * 4 + r) * OUT + j] = acc[ni][r] + bb;
        }
        __syncthreads();
    }
}

// ===========================================================================
// Fallback pipeline (byte-identical to R9, best-known 170.1 us)
// ===========================================================================
__global__ __launch_bounds__(256) void prep_kernel(
    const float* __restrict__ feat, const float* __restrict__ w1,
    const float* __restrict__ wf, const int* __restrict__ dst,
    ushort_t* __restrict__ abig, ushort_t* __restrict__ btp,
    ushort_t* __restrict__ btf, int* __restrict__ row_ptr,
    int n, int e, int nb0, int nb1, int nb2)
{
    const int b = blockIdx.x, t = threadIdx.x;
    if (b < nb0) {
        int i = b * 256 + t;
        if (i >= n * 16) return;
        int row = i >> 4, c = (i & 15) * 8;
        float4 a = *(const float4*)(feat + (size_t)row * F + c);
        float4 bb = *(const float4*)(feat + (size_t)row * F + c + 4);
        *(uint4*)(abig + (size_t)row * 256 + c) =
            make_uint4(pk2(a.x, a.y), pk2(a.z, a.w), pk2(bb.x, bb.y), pk2(bb.z, bb.w));
    } else if (b < nb0 + nb1) {
        int idx = (b - nb0) * 256 + t;
        int j = idx >> 7, k = idx & 127;
        float v = (j < F) ? w1[(size_t)k * F + j]
                          : w1[(size_t)(F + k) * F + (j - F)];
        btp[idx] = f2bf(v);
    } else if (b < nb0 + nb1 + nb2) {
        int idx = (b - nb0 - nb1) * 256 + t;
        int j = idx >> 8, k = idx & 255;
        btf[idx] = f2bf(wf[(size_t)k * F + j]);
    } else {
        int i = (b - nb0 - nb1 - nb2) * 256 + t;
        if (i >= e) return;
        int d = dst[i];
        int prev = (i == 0) ? -1 : dst[i - 1];
        for (int v = prev + 1; v <= d; ++v) row_ptr[v] = i;
        if (i == e - 1) {
            for (int v = d + 1; v <= n; ++v) row_ptr[v] = e;
        }
    }
}

__global__ __launch_bounds__(256) void proj_gemm_kernel(
    const ushort_t* __restrict__ abig, const ushort_t* __restrict__ btp,
    const float* __restrict__ b1, ushort_t* __restrict__ e_dst,
    ushort_t* __restrict__ srcpack, int n)
{
    __shared__ ushort_t As[64 * PST];
    __shared__ ushort_t Ep[4][16 * 80];
    const int t = threadIdx.x;
    const int wv = t >> 6, lane = t & 63;
    const int lm = lane & 15, quad = lane >> 4;
    const int row0 = blockIdx.x * 64, col0 = wv * 64;

#pragma unroll
    for (int k = 0; k < 4; ++k) {
        int l = k * 256 + t;
        int r = l >> 4, ch = l & 15;
        uint4 d = make_uint4(0, 0, 0, 0);
        if (row0 + r < n) d = *(const uint4*)(abig + (size_t)(row0 + r) * 256 + ch * 8);
        *(uint4*)(As + r * PST + ch * 8) = d;
    }
    __syncthreads();

    bfrag bfr[4][4];
#pragma unroll
    for (int ks = 0; ks < 4; ++ks)
#pragma unroll
        for (int ni = 0; ni < 4; ++ni)
            bfr[ks][ni] = *(const bfrag*)(btp + (size_t)(col0 + ni * 16 + lm) * 128
                                          + ks * 32 + quad * 8);

    ffrag acc[4][4];
#pragma unroll
    for (int mi = 0; mi < 4; ++mi)
#pragma unroll
        for (int ni = 0; ni < 4; ++ni) acc[mi][ni] = (ffrag){0.f, 0.f, 0.f, 0.f};

#pragma unroll
    for (int ks = 0; ks < 4; ++ks)
#pragma unroll
        for (int mi = 0; mi < 4; ++mi) {
            bfrag af = *(const bfrag*)(As + (mi * 16 + lm) * PST + ks * 32 + quad * 8);
#pragma unroll
            for (int ni = 0; ni < 4; ++ni)
                acc[mi][ni] = __builtin_amdgcn_mfma_f32_16x16x32_bf16(
                    af, bfr[ks][ni], acc[mi][ni], 0, 0, 0);
        }

    float bias[4];
#pragma unroll
    for (int ni = 0; ni < 4; ++ni)
        bias[ni] = (col0 < F) ? b1[col0 + ni * 16 + lm] : 0.f;

#pragma unroll
    for (int mi = 0; mi < 4; ++mi) {
#pragma unroll
        for (int ni = 0; ni < 4; ++ni)
#pragma unroll
            for (int r = 0; r < 4; ++r)
                Ep[wv][(quad * 4 + r) * 80 + ni * 16 + lm] =
                    f2bf(__expf(2.f * (acc[mi][ni][r] + bias[ni])));

        if (col0 < F) {
#pragma unroll
            for (int ps = 0; ps < 2; ++ps) {
                int rl = ps * 8 + (lane >> 3), co = (lane & 7) * 8;
                uint4 vv = *(const uint4*)(&Ep[wv][rl * 80 + co]);
                int grow = row0 + mi * 16 + rl;
                if (grow < n)
                    *(uint4*)(e_dst + (size_t)grow * F + col0 + co) = vv;
            }
        } else {
            const int cbase = (col0 - F) >> 2;
#pragma unroll
            for (int ps = 0; ps < 4; ++ps) {
                int rl = ps * 4 + (lane >> 4);
                int c  = lane & 15;
                int cg2 = cbase + c;
                uint2 es = *(const uint2*)(&Ep[wv][rl * 80 + c * 4]);
                uint2 ft = *(const uint2*)(As + (mi * 16 + rl) * PST + cg2 * 4);
                int grow = row0 + mi * 16 + rl;
                if (grow < n)
                    *(uint4*)(srcpack + (size_t)grow * 256 + cg2 * 8) =
                        make_uint4(es.x, es.y, ft.x, ft.y);
            }
        }
    }
}

__global__ __launch_bounds__(256) void fused_kernel(
    const ushort_t* __restrict__ e_dst, const ushort_t* __restrict__ srcpack,
    const int* __restrict__ src, const int* __restrict__ row_ptr,
    const float* __restrict__ w2, ushort_t* __restrict__ abig, int n)
{
    const int v = (int)((blockIdx.x * 256u + threadIdx.x) >> 5);
    const int fl = threadIdx.x & 31;
    const int sbase = threadIdx.x & 32;

    const float4 wv4 = ((const float4*)w2)[fl];
    const float w0 = wv4.x, w1_ = wv4.y, w2_ = wv4.z, w3_ = wv4.w;
    float sw = w0 + w1_ + w2_ + w3_;
    float aw = fabsf(w0) + fabsf(w1_) + fabsf(w2_) + fabsf(w3_);
#pragma unroll
    for (int off = 16; off; off >>= 1) {
        sw += __shfl_xor(sw, off, 64);
        aw += __shfl_xor(aw, off, 64);
    }
    const float K = sw - aw;

    if (v >= n) return;
    const int begin = row_ptr[v], end = row_ptr[v + 1];

    const uint2 ud = *(const uint2*)(e_dst + (size_t)v * F + fl * 4);
    const float ea0 = bf_lo(ud.x), ea1 = bf_hi(ud.x);
    const float ea2 = bf_lo(ud.y), ea3 = bf_hi(ud.y);

    float s = 0.f, a0 = 0.f, a1 = 0.f, a2 = 0.f, a3 = 0.f;

    for (int cb = begin; cb < end; cb += 32) {
        const int clen = min(32, end - cb);
        const int sv = (fl < clen) ? src[cb + fl] : 0;
        int jj = 0;
        for (; jj + 4 <= clen; jj += 4) {
            uint4 u[4];
#pragma unroll
            for (int q = 0; q < 4; ++q) {
                const int sq = __shfl(sv, sbase + jj + q, 64);
                u[q] = ((const uint4*)(srcpack + (size_t)sq * 256))[fl];
            }
            float p[4];
#pragma unroll
            for (int q = 0; q < 4; ++q) {
                float r;
                r = __builtin_amdgcn_rcpf(fmaf(ea0, bf_lo(u[q].x), 1.f)); p[q] = w0 * r;
                r = __builtin_amdgcn_rcpf(fmaf(ea1, bf_hi(u[q].x), 1.f)); p[q] = fmaf(w1_, r, p[q]);
                r = __builtin_amdgcn_rcpf(fmaf(ea2, bf_lo(u[q].y), 1.f)); p[q] = fmaf(w2_, r, p[q]);
                r = __builtin_amdgcn_rcpf(fmaf(ea3, bf_hi(u[q].y), 1.f)); p[q] = fmaf(w3_, r, p[q]);
            }
#pragma unroll
            for (int off = 16; off; off >>= 1) {
#pragma unroll
                for (int q = 0; q < 4; ++q) p[q] += __shfl_xor(p[q], off, 64);
            }
            float g[4];
#pragma unroll
            for (int q = 0; q < 4; ++q) g[q] = __expf(fmaf(-2.f, p[q], K));
            s += (g[0] + g[1]) + (g[2] + g[3]);
#pragma unroll
            for (int q = 0; q < 4; ++q) {
                a0 = fmaf(g[q], bf_lo(u[q].z), a0);
                a1 = fmaf(g[q], bf_hi(u[q].z), a1);
                a2 = fmaf(g[q], bf_lo(u[q].w), a2);
                a3 = fmaf(g[q], bf_hi(u[q].w), a3);
            }
        }
        for (; jj < clen; ++jj) {
            const int s0 = __shfl(sv, sbase + jj, 64);
            const uint4 u0 = ((const uint4*)(srcpack + (size_t)s0 * 256))[fl];
            float r, p0;
            r = __builtin_amdgcn_rcpf(fmaf(ea0, bf_lo(u0.x), 1.f)); p0 = w0 * r;
            r = __builtin_amdgcn_rcpf(fmaf(ea1, bf_hi(u0.x), 1.f)); p0 = fmaf(w1_, r, p0);
            r = __builtin_amdgcn_rcpf(fmaf(ea2, bf_lo(u0.y), 1.f)); p0 = fmaf(w2_, r, p0);
            r = __builtin_amdgcn_rcpf(fmaf(ea3, bf_hi(u0.y), 1.f)); p0 = fmaf(w3_, r, p0);
#pragma unroll
            for (int off = 16; off; off >>= 1) p0 += __shfl_xor(p0, off, 64);
            const float g0 = __expf(fmaf(-2.f, p0, K));
            s += g0;
            a0 = fmaf(g0, bf_lo(u0.z), a0);
            a1 = fmaf(g0, bf_hi(u0.z), a1);
            a2 = fmaf(g0, bf_lo(u0.w), a2);
            a3 = fmaf(g0, bf_hi(u0.w), a3);
        }
    }

    const float inv = (end > begin) ? 1.f / s : 0.f;
    *(ushort4*)(abig + (size_t)v * 256 + 128 + fl * 4) =
        make_ushort4(f2bf(a0 * inv), f2bf(a1 * inv), f2bf(a2 * inv), f2bf(a3 * inv));
}

__global__ __launch_bounds__(256) void out_gemm_kernel(
    const ushort_t* __restrict__ abig, const ushort_t* __restrict__ btf,
    const float* __restrict__ bfv, float* __restrict__ out, int n)
{
    __shared__ ushort_t As[64 * FOST];
    const int t = threadIdx.x;
    const int wv = t >> 6, lane = t & 63;
    const int lm = lane & 15, quad = lane >> 4;
    const int row0 = blockIdx.x * 64, col0 = wv * 32;

#pragma unroll
    for (int k = 0; k < 8; ++k) {
        int l = k * 256 + t;
        int r = l >> 5, ch = l & 31;
        uint4 d = make_uint4(0, 0, 0, 0);
        if (row0 + r < n) d = *(const uint4*)(abig + (size_t)(row0 + r) * 256 + ch * 8);
        *(uint4*)(As + r * FOST + ch * 8) = d;
    }
    __syncthreads();

    bfrag bfr[8][2];
#pragma unroll
    for (int ks = 0; ks < 8; ++ks)
#pragma unroll
        for (int ni = 0; ni < 2; ++ni)
            bfr[ks][ni] = *(const bfrag*)(btf + (size_t)(col0 + ni * 16 + lm) * 256
                                          + ks * 32 + quad * 8);

    ffrag acc[4][2];
#pragma unroll
    for (int mi = 0; mi < 4; ++mi)
#pragma unroll
        for (int ni = 0; ni < 2; ++ni) acc[mi][ni] = (ffrag){0.f, 0.f, 0.f, 0.f};

#pragma unroll
    for (int ks = 0; ks < 8; ++ks)
#pragma unroll
        for (int mi = 0; mi < 4; ++mi) {
            bfrag af = *(const bfrag*)(As + (mi * 16 + lm) * FOST + ks * 32 + quad * 8);
#pragma unroll
            for (int ni = 0; ni < 2; ++ni)
                acc[mi][ni] = __builtin_amdgcn_mfma_f32_16x16x32_bf16(
                    af, bfr[ks][ni], acc[mi][ni], 0, 0, 0);
        }

#pragma unroll
    for (int ni = 0; ni < 2; ++ni) {
        const int j = col0 + ni * 16 + lm;
        const float bb = bfv[j];
#pragma unroll
        for (int mi = 0; mi < 4; ++mi)
#pragma unroll
            for (int r = 0; r < 4; ++r) {
                int grow = row0 + mi * 16 + quad * 4 + r;
                if (grow < n) out[(size_t)grow * OUT + j] = acc[mi][ni][r] + bb;
            }
    }
}

// ---------------------------------------------------------------------------
extern "C" void kernel_launch(void* const* d_in, const int* in_sizes, int n_in,
                              void* d_out, int out_size, void* d_ws, size_t ws_size,
                              hipStream_t stream)
{
    const float* feat = (const float*)d_in[0];
    const int*   src  = (const int*)d_in[1];
    const int*   dst  = (const int*)d_in[2];
    const float* w1   = (const float*)d_in[3];
    const float* b1   = (const float*)d_in[4];
    const float* w2   = (const float*)d_in[5];
    const float* b2   = (const float*)d_in[6];  (void)b2; // cancels in softmax
    const float* wf   = (const float*)d_in[7];
    const float* bfv  = (const float*)d_in[8];
    float* out = (float*)d_out;

    int n = in_sizes[0] / F;   // 40000
    int e = in_sizes[1];       // 640000

    ushort_t* abig    = (ushort_t*)d_ws;                   // n*256 bf16 [feat|neigh]
    ushort_t* e_dst   = abig + (size_t)n * 256;            // n*128 bf16
    ushort_t* srcpack = e_dst + (size_t)n * 128;           // n*256 bf16 interleaved
    ushort_t* btp     = srcpack + (size_t)n * 256;         // 256*128 bf16 col-major
    ushort_t* btf     = btp + 32768;                       // 128*256 bf16 col-major
    int* row_ptr      = (int*)(btf + 32768);               // n+1

    // ---- try cooperative giga kernel, clamped to true co-residency ----
    hipError_t lerr = hipErrorUnknown;
    int maxPerCU = 0;
    hipError_t qerr = hipOccupancyMaxActiveBlocksPerMultiprocessor(
        &maxPerCU, giga_kernel, 256, 0);
    if (qerr == hipSuccess && maxPerCU > 0) {
        int grid = maxPerCU * 256;          // 256 CUs on MI355X
        if (grid > 1024) grid = 1024;
        void* args[] = {
            (void*)&feat, (void*)&w1, (void*)&b1, (void*)&w2, (void*)&wf,
            (void*)&bfv, (void*)&src, (void*)&dst, (void*)&out,
            (void*)&abig, (void*)&e_dst, (void*)&srcpack, (void*)&btp,
            (void*)&btf, (void*)&row_ptr, (void*)&n, (void*)&e
        };
        lerr = hipLaunchCooperativeKernel((void*)giga_kernel, dim3(grid),
                                          dim3(256), args, 0, stream);
    }
    if (lerr == hipSuccess) return;

    // ---- fallback: R9 pipeline (known-good 170 us) ----
    const int nb0 = (n * 16 + 255) / 256;
    const int nb1 = 128, nb2 = 128;
    const int nb3 = (e + 255) / 256;
    prep_kernel<<<nb0 + nb1 + nb2 + nb3, 256, 0, stream>>>(
        feat, w1, wf, dst, abig, btp, btf, row_ptr, n, e, nb0, nb1, nb2);
    proj_gemm_kernel<<<(n + 63) / 64, 256, 0, stream>>>(
        abig, btp, b1, e_dst, srcpack, n);
    fused_kernel<<<(n + 7) / 8, 256, 0, stream>>>(
        e_dst, srcpack, src, row_ptr, w2, abig, n);
    out_gemm_kernel<<<(n + 63) / 64, 256, 0, stream>>>(abig, btf, bfv, out, n);
}